// Round 18
// baseline (64.241 us; speedup 1.0000x reference)
//
#include <hip/hip_runtime.h>
#include <hip/hip_bf16.h>

#define N 192
#define CZ 128
#define NH 4
#define CH 32
#define WIN 16
#define NROWS (N*N)   // 36864

typedef __attribute__((ext_vector_type(8))) short bf16x8;
typedef __attribute__((ext_vector_type(4))) float f32x4;

static __device__ __forceinline__ ushort f2bf(float x){
    union{float f; unsigned u;} a; a.f = x;
    unsigned r = a.u + 0x7fffu + ((a.u>>16)&1u);   // RNE
    return (ushort)(r>>16);
}
static __device__ __forceinline__ float bf2f(ushort s){
    union{unsigned u; float f;} a; a.u = ((unsigned)s)<<16;
    return a.f;
}

// ---------------- K1: LN + triangle-bias projection, with weight-packing piggybacked ----------------
// Blocks 0..39 additionally pack one-eighth of one weight matrix into MFMA-fragment order.
__global__ __launch_bounds__(256) void k_tb_pack(
    const float* __restrict__ z, const float* __restrict__ lnw, const float* __restrict__ lnb,
    const float* __restrict__ wbias, float* __restrict__ tb,
    const float* __restrict__ wq, const float* __restrict__ wk,
    const float* __restrict__ wv, const float* __restrict__ wg,
    const float* __restrict__ wo, ushort* __restrict__ WP)
{
    const int tid = threadIdx.x;
    if (blockIdx.x < 40) {
        const int m = blockIdx.x >> 3;
        const float* W = (m==0)?wq:(m==1)?wk:(m==2)?wv:(m==3)?wg:wo;
        const int f = (blockIdx.x & 7)*256 + tid;       // fragment index 0..2047
        const int nt = f >> 8, ks = (f >> 6) & 3, lane8 = f & 63;
        const int col = nt*16 + (lane8 & 15);
        const int r0  = ks*32 + (lane8 >> 4)*8;
        ushort tmp[8];
        #pragma unroll
        for (int i=0; i<8; i++) tmp[i] = f2bf(W[(size_t)(r0+i)*CZ + col]);
        *(uint4*)(WP + (size_t)m*16384 + (size_t)f*8) = *(uint4*)tmp;
    }
    const int wave = tid >> 6, lane = tid & 63;
    const int r  = wave*4 + (lane >> 4);
    const int li = lane & 15;
    const int row = blockIdx.x*16 + r;
    const float* zr = z + (size_t)row*CZ + li*8;
    float4 a = ((const float4*)zr)[0];
    float4 b = ((const float4*)zr)[1];
    float s  = a.x+a.y+a.z+a.w + b.x+b.y+b.z+b.w;
    float s2 = a.x*a.x+a.y*a.y+a.z*a.z+a.w*a.w + b.x*b.x+b.y*b.y+b.z*b.z+b.w*b.w;
    #pragma unroll
    for (int off=1; off<16; off<<=1) { s += __shfl_xor(s, off); s2 += __shfl_xor(s2, off); }
    const float mu   = s * (1.f/CZ);
    const float rstd = rsqrtf(s2*(1.f/CZ) - mu*mu + 1e-5f);
    const int c0 = li*8;
    float vals[8] = {a.x,a.y,a.z,a.w,b.x,b.y,b.z,b.w};
    float tbp[4] = {0.f,0.f,0.f,0.f};
    #pragma unroll
    for (int t=0; t<8; t++) {
        const float nv = (vals[t]-mu)*rstd*lnw[c0+t] + lnb[c0+t];
        float4 wb4 = *(const float4*)(wbias + (c0+t)*4);
        tbp[0] += nv*wb4.x; tbp[1] += nv*wb4.y;
        tbp[2] += nv*wb4.z; tbp[3] += nv*wb4.w;
    }
    #pragma unroll
    for (int off=1; off<16; off<<=1) {
        #pragma unroll
        for (int h=0; h<4; h++) tbp[h] += __shfl_xor(tbp[h], off);
    }
    if (li == 0) *(float4*)(tb + (size_t)row*4) = make_float4(tbp[0],tbp[1],tbp[2],tbp[3]);
}

// ---------------- K2: fused LN + Q/K/V/G proj + attention + gate + out-GEMM ----------------
// 512 threads, LDS 46.7KB -> 3 blocks/CU (1152 blocks = 1.5 rounds vs 2.25 at R17's 61KB).
// gb lives in registers across the proj barrier, then lands in the dead zlds region.
__global__ __launch_bounds__(512, 6) void k_fused(
    const float* __restrict__ z, const float* __restrict__ lnw, const float* __restrict__ lnb,
    const float* __restrict__ mask, const float* __restrict__ tb,
    const ushort* __restrict__ WP, const float* __restrict__ bg,
    const float* __restrict__ bout, float* __restrict__ out)
{
    __shared__ ushort zlds[48][132];     // LN'd halo rows -> later gb, then po
    __shared__ ushort kl[48][132];       // K halo, [row][head*32+c] (+4 pad)
    __shared__ ushort vl[48][132];
    __shared__ ushort qb[32][132];       // Q for own 32 rows
    __shared__ float  ml[48];
    ushort (*gpo)[132] = zlds;           // gate / gated-output alias

    const int i   = blockIdx.y;
    const int j0  = blockIdx.x * 32;
    const int tid = threadIdx.x;
    const int wid = tid >> 6, lane = tid & 63;
    const int l16 = lane & 15, lk = lane >> 4;

    // ---- Phase 1: LN of 48 halo slots (2 passes of 32 rows; 16 lanes x 8ch per row) ----
    #pragma unroll
    for (int pass = 0; pass < 2; ++pass) {
        const int r = pass*32 + (tid >> 4);
        if (r < 48) {
            const int li  = tid & 15;
            const int jj  = j0 - 8 + r;
            const int jjc = min(max(jj, 0), N-1);
            const float* zr = z + ((size_t)i*N + jjc)*CZ + li*8;
            float4 a = ((const float4*)zr)[0];
            float4 b = ((const float4*)zr)[1];
            float s  = a.x+a.y+a.z+a.w + b.x+b.y+b.z+b.w;
            float s2 = a.x*a.x+a.y*a.y+a.z*a.z+a.w*a.w + b.x*b.x+b.y*b.y+b.z*b.z+b.w*b.w;
            #pragma unroll
            for (int off=1; off<16; off<<=1) { s += __shfl_xor(s, off); s2 += __shfl_xor(s2, off); }
            const float mu   = s * (1.f/CZ);
            const float rstd = rsqrtf(s2*(1.f/CZ) - mu*mu + 1e-5f);
            const int c0 = li*8;
            float vals[8] = {a.x,a.y,a.z,a.w,b.x,b.y,b.z,b.w};
            uint4 pk; ushort* ph = (ushort*)&pk;
            #pragma unroll
            for (int t=0; t<8; t++)
                ph[t] = f2bf((vals[t]-mu)*rstd*lnw[c0+t] + lnb[c0+t]);
            *(uint4*)&zlds[r][c0] = pk;
        }
    }
    if (tid < 47) {
        const int jj  = j0 - 8 + tid;
        const int jjc = min(max(jj, 0), N-1);
        const bool ok = (jj >= 0) && (jj < N) && (mask[(size_t)i*N + jjc] > 0.f);
        ml[tid] = ok ? 0.f : -1e9f;
    }
    __syncthreads();                                    // B1

    // ---- Phase 2: projections. 10 tile-jobs over 8 waves (5 per half). ----
    uint2 gst0[2], gst1[2];
    {
        const int cw   = wid & 3;     // column quarter (= head)
        const int half = wid >> 2;

        bf16x8 bfrag[2][4];
        auto loadB = [&](int m) {
            #pragma unroll
            for (int nt2=0; nt2<2; nt2++)
                #pragma unroll
                for (int ks=0; ks<4; ks++)
                    bfrag[nt2][ks] = *(const bf16x8*)(WP + (size_t)m*16384 + (cw*2+nt2)*2048 + ks*512 + lane*8);
        };
        auto projKV = [&](int slot0, ushort (*dst)[132]) {
            bf16x8 af[4];
            #pragma unroll
            for (int ks=0; ks<4; ks++)
                af[ks] = *(const bf16x8*)&zlds[slot0 + l16][ks*32 + lk*8];
            #pragma unroll
            for (int nt2=0; nt2<2; nt2++) {
                f32x4 acc = {0.f,0.f,0.f,0.f};
                #pragma unroll
                for (int ks=0; ks<4; ks++)   // swapped -> C^T: row=slot0+l16
                    acc = __builtin_amdgcn_mfma_f32_16x16x32_bf16(bfrag[nt2][ks], af[ks], acc, 0, 0, 0);
                uint2 pk2;
                pk2.x = (unsigned)f2bf(acc[0]) | ((unsigned)f2bf(acc[1])<<16);
                pk2.y = (unsigned)f2bf(acc[2]) | ((unsigned)f2bf(acc[3])<<16);
                *(uint2*)&dst[slot0 + l16][cw*32 + nt2*16 + lk*4] = pk2;
            }
        };
        auto projQ = [&](int slot0) {
            bf16x8 af[4];
            #pragma unroll
            for (int ks=0; ks<4; ks++)
                af[ks] = *(const bf16x8*)&zlds[slot0 + l16][ks*32 + lk*8];
            #pragma unroll
            for (int nt2=0; nt2<2; nt2++) {
                f32x4 acc = {0.f,0.f,0.f,0.f};
                #pragma unroll
                for (int ks=0; ks<4; ks++)
                    acc = __builtin_amdgcn_mfma_f32_16x16x32_bf16(bfrag[nt2][ks], af[ks], acc, 0, 0, 0);
                uint2 pk2;
                pk2.x = (unsigned)f2bf(acc[0]) | ((unsigned)f2bf(acc[1])<<16);
                pk2.y = (unsigned)f2bf(acc[2]) | ((unsigned)f2bf(acc[3])<<16);
                *(uint2*)&qb[slot0 - 8 + l16][cw*32 + nt2*16 + lk*4] = pk2;
            }
        };
        auto projG = [&](int slot0, uint2* gs) {
            float4 bg4[2];
            #pragma unroll
            for (int nt2=0; nt2<2; nt2++)
                bg4[nt2] = *(const float4*)(bg + cw*32 + nt2*16 + lk*4);
            bf16x8 af[4];
            #pragma unroll
            for (int ks=0; ks<4; ks++)
                af[ks] = *(const bf16x8*)&zlds[slot0 + l16][ks*32 + lk*8];
            #pragma unroll
            for (int nt2=0; nt2<2; nt2++) {
                f32x4 acc = {0.f,0.f,0.f,0.f};
                #pragma unroll
                for (int ks=0; ks<4; ks++)
                    acc = __builtin_amdgcn_mfma_f32_16x16x32_bf16(bfrag[nt2][ks], af[ks], acc, 0, 0, 0);
                const float v0 = 1.f/(1.f + __expf(-(acc[0] + bg4[nt2].x)));
                const float v1 = 1.f/(1.f + __expf(-(acc[1] + bg4[nt2].y)));
                const float v2 = 1.f/(1.f + __expf(-(acc[2] + bg4[nt2].z)));
                const float v3 = 1.f/(1.f + __expf(-(acc[3] + bg4[nt2].w)));
                uint2 pk2;
                pk2.x = (unsigned)f2bf(v0) | ((unsigned)f2bf(v1)<<16);
                pk2.y = (unsigned)f2bf(v2) | ((unsigned)f2bf(v3)<<16);
                gs[nt2] = pk2;
            }
        };

        if (half == 0) {
            loadB(1); projKV(0, kl); projKV(16, kl); projKV(32, kl);   // K
            loadB(2); projKV(0, vl); projKV(16, vl);                   // V (part)
        } else {
            loadB(2); projKV(32, vl);                                  // V (rest)
            loadB(0); projQ(8); projQ(24);                             // Q
            loadB(3); projG(8, gst0); projG(24, gst1);                 // G -> regs
        }
    }
    __syncthreads();                                    // B2 (zlds now dead)
    if ((wid >> 2) == 1) {                              // land G into zlds region
        const int cw = wid & 3;
        *(uint2*)&gpo[l16     ][cw*32      + lk*4] = gst0[0];
        *(uint2*)&gpo[l16     ][cw*32 + 16 + lk*4] = gst0[1];
        *(uint2*)&gpo[16 + l16][cw*32      + lk*4] = gst1[0];
        *(uint2*)&gpo[16 + l16][cw*32 + 16 + lk*4] = gst1[1];
    }

    // ---- Phase 3: windowed attention (thread = (jloc, h, cq)): 8 channels each ----
    const int cq   = tid & 3;
    const int h    = (tid >> 2) & 3;
    const int jloc = tid >> 4;
    const int j    = j0 + jloc;
    const int c0l  = cq * 8;

    float qv[8];
    {
        uint4 q1 = *(const uint4*)&qb[jloc][h*32 + c0l];
        const ushort* s1 = (const ushort*)&q1;
        #pragma unroll
        for (int t=0; t<8; t++) qv[t] = bf2f(s1[t]);
    }

    const float scale = 0.17677669529663688f; // 1/sqrt(32)
    float lg[WIN];
    #pragma unroll
    for (int w=0; w<WIN; w++) {
        const int rel = jloc + w;
        float dot = 0.f;
        {
            uint4 kv = *(const uint4*)&kl[rel][h*32 + c0l];
            const ushort* kp = (const ushort*)&kv;
            #pragma unroll
            for (int t=0; t<8; t++) dot += qv[t]*bf2f(kp[t]);
        }
        dot += __shfl_xor(dot, 1);
        dot += __shfl_xor(dot, 2);          // combine the four c-quarters
        const int jj  = j - 8 + w;
        const int jjc = min(max(jj, 0), N-1);
        lg[w] = dot*scale + tb[((size_t)j*N + jjc)*4 + h] + ml[rel];
    }
    float mx = lg[0];
    #pragma unroll
    for (int w=1; w<WIN; w++) mx = fmaxf(mx, lg[w]);
    float sum = 0.f;
    #pragma unroll
    for (int w=0; w<WIN; w++) { lg[w] = __expf(lg[w]-mx); sum += lg[w]; }
    const float inv = 1.f/sum;

    float o[8];
    #pragma unroll
    for (int c=0; c<8; c++) o[c] = 0.f;
    #pragma unroll
    for (int w=0; w<WIN; w++) {
        const float p   = lg[w]*inv;
        const int   rel = jloc + w;
        uint4 vv = *(const uint4*)&vl[rel][h*32 + c0l];
        const ushort* vp = (const ushort*)&vv;
        #pragma unroll
        for (int t=0; t<8; t++) o[t] += p*bf2f(vp[t]);
    }

    // prefetch out-GEMM B + biases while waiting
    const int rt  = wid >> 2;
    const int cwo = wid & 3;
    bf16x8 bf4[2][4];
    float4 bo4[2];
    #pragma unroll
    for (int nt2=0; nt2<2; nt2++) {
        #pragma unroll
        for (int ks=0; ks<4; ks++)
            bf4[nt2][ks] = *(const bf16x8*)(WP + (size_t)4*16384 + (cwo*2+nt2)*2048 + ks*512 + lane*8);
        bo4[nt2] = *(const float4*)(bout + cwo*32 + nt2*16 + lk*4);
    }
    __syncthreads();                                    // B3: G writes visible

    {
        uint4 g1 = *(const uint4*)&gpo[jloc][h*32 + c0l];
        const ushort* s1 = (const ushort*)&g1;
        uint4 o1; ushort* p1 = (ushort*)&o1;
        #pragma unroll
        for (int t=0; t<8; t++) p1[t] = f2bf(o[t] * bf2f(s1[t]));
        *(uint4*)&gpo[jloc][h*32 + c0l] = o1;           // same element: read-then-write by this thread
    }
    __syncthreads();                                    // B4

    // ---- Phase 4: out-GEMM. Wave = (rt, col-quarter): 1 row-tile x 32 cols each ----
    {
        bf16x8 af[4];
        #pragma unroll
        for (int ks=0; ks<4; ks++)
            af[ks] = *(const bf16x8*)&gpo[rt*16 + l16][ks*32 + lk*8];
        const size_t orow = (size_t)(i*N + j0 + rt*16 + l16)*CZ;
        #pragma unroll
        for (int nt2=0; nt2<2; nt2++) {
            f32x4 acc = {0.f,0.f,0.f,0.f};
            #pragma unroll
            for (int ks=0; ks<4; ks++)   // swapped -> C^T: row=l16, 4 consecutive cols
                acc = __builtin_amdgcn_mfma_f32_16x16x32_bf16(bf4[nt2][ks], af[ks], acc, 0, 0, 0);
            float4 ov;
            ov.x = acc[0] + bo4[nt2].x; ov.y = acc[1] + bo4[nt2].y;
            ov.z = acc[2] + bo4[nt2].z; ov.w = acc[3] + bo4[nt2].w;
            *(float4*)(out + orow + cwo*32 + nt2*16 + lk*4) = ov;
        }
    }
}

extern "C" void kernel_launch(void* const* d_in, const int* in_sizes, int n_in,
                              void* d_out, int out_size, void* d_ws, size_t ws_size,
                              hipStream_t stream)
{
    const float* z    = (const float*)d_in[0];
    const float* mask = (const float*)d_in[1];
    const float* lnw  = (const float*)d_in[2];
    const float* lnb  = (const float*)d_in[3];
    const float* wq   = (const float*)d_in[4];
    const float* wk   = (const float*)d_in[5];
    const float* wv   = (const float*)d_in[6];
    const float* wb   = (const float*)d_in[7];
    const float* wg   = (const float*)d_in[8];
    const float* bg   = (const float*)d_in[9];
    const float* wo   = (const float*)d_in[10];
    const float* bo   = (const float*)d_in[11];

    float*  tb = (float*)d_ws;                      // f32 [NROWS][4]
    ushort* WP = (ushort*)(tb + (size_t)NROWS*4);   // 5 x 16384 bf16, fragment-ordered
    if (ws_size < (size_t)NROWS*4*sizeof(float) + 5*16384*sizeof(ushort)) return;

    k_tb_pack<<<NROWS/16, 256, 0, stream>>>(z, lnw, lnb, wb, tb, wq, wk, wv, wg, wo, WP);
    k_fused  <<<dim3(N/32, N), 512, 0, stream>>>(z, lnw, lnb, mask, tb, WP, bg, bo, (float*)d_out);
}

// Round 19
// 49.826 us; speedup vs baseline: 1.2893x; 1.2893x over previous
//
#include <hip/hip_runtime.h>
#include <hip/hip_bf16.h>

#define N 192
#define CZ 128
#define NH 4
#define CH 32
#define WIN 16
#define NROWS (N*N)   // 36864

typedef __attribute__((ext_vector_type(8))) short bf16x8;
typedef __attribute__((ext_vector_type(4))) float f32x4;

static __device__ __forceinline__ ushort f2bf(float x){
    union{float f; unsigned u;} a; a.f = x;
    unsigned r = a.u + 0x7fffu + ((a.u>>16)&1u);   // RNE
    return (ushort)(r>>16);
}
static __device__ __forceinline__ float bf2f(ushort s){
    union{unsigned u; float f;} a; a.u = ((unsigned)s)<<16;
    return a.f;
}

// ---------------- K1: LN + triangle-bias projection, weight-packing piggybacked ----------------
// Blocks 0..39 additionally pack one-eighth of one weight matrix into MFMA-fragment order.
__global__ __launch_bounds__(256) void k_tb_pack(
    const float* __restrict__ z, const float* __restrict__ lnw, const float* __restrict__ lnb,
    const float* __restrict__ wbias, float* __restrict__ tb,
    const float* __restrict__ wq, const float* __restrict__ wk,
    const float* __restrict__ wv, const float* __restrict__ wg,
    const float* __restrict__ wo, ushort* __restrict__ WP)
{
    const int tid = threadIdx.x;
    if (blockIdx.x < 40) {
        const int m = blockIdx.x >> 3;
        const float* W = (m==0)?wq:(m==1)?wk:(m==2)?wv:(m==3)?wg:wo;
        const int f = (blockIdx.x & 7)*256 + tid;       // fragment index 0..2047
        const int nt = f >> 8, ks = (f >> 6) & 3, lane8 = f & 63;
        const int col = nt*16 + (lane8 & 15);
        const int r0  = ks*32 + (lane8 >> 4)*8;
        ushort tmp[8];
        #pragma unroll
        for (int i=0; i<8; i++) tmp[i] = f2bf(W[(size_t)(r0+i)*CZ + col]);
        *(uint4*)(WP + (size_t)m*16384 + (size_t)f*8) = *(uint4*)tmp;
    }
    const int wave = tid >> 6, lane = tid & 63;
    const int r  = wave*4 + (lane >> 4);
    const int li = lane & 15;
    const int row = blockIdx.x*16 + r;
    const float* zr = z + (size_t)row*CZ + li*8;
    float4 a = ((const float4*)zr)[0];
    float4 b = ((const float4*)zr)[1];
    float s  = a.x+a.y+a.z+a.w + b.x+b.y+b.z+b.w;
    float s2 = a.x*a.x+a.y*a.y+a.z*a.z+a.w*a.w + b.x*b.x+b.y*b.y+b.z*b.z+b.w*b.w;
    #pragma unroll
    for (int off=1; off<16; off<<=1) { s += __shfl_xor(s, off); s2 += __shfl_xor(s2, off); }
    const float mu   = s * (1.f/CZ);
    const float rstd = rsqrtf(s2*(1.f/CZ) - mu*mu + 1e-5f);
    const int c0 = li*8;
    float vals[8] = {a.x,a.y,a.z,a.w,b.x,b.y,b.z,b.w};
    float tbp[4] = {0.f,0.f,0.f,0.f};
    #pragma unroll
    for (int t=0; t<8; t++) {
        const float nv = (vals[t]-mu)*rstd*lnw[c0+t] + lnb[c0+t];
        float4 wb4 = *(const float4*)(wbias + (c0+t)*4);
        tbp[0] += nv*wb4.x; tbp[1] += nv*wb4.y;
        tbp[2] += nv*wb4.z; tbp[3] += nv*wb4.w;
    }
    #pragma unroll
    for (int off=1; off<16; off<<=1) {
        #pragma unroll
        for (int h=0; h<4; h++) tbp[h] += __shfl_xor(tbp[h], off);
    }
    if (li == 0) *(float4*)(tb + (size_t)row*4) = make_float4(tbp[0],tbp[1],tbp[2],tbp[3]);
}

// ---------------- K2: fused LN + Q/K/V/G proj + attention + gate + out-GEMM ----------------
// R17-proven version: 512 threads, launch_bounds(512,4) -> VGPR<=128 (bfrag stays resident),
// [NH][40] conflict-free K/V layouts, gb in LDS.
__global__ __launch_bounds__(512, 4) void k_fused(
    const float* __restrict__ z, const float* __restrict__ lnw, const float* __restrict__ lnb,
    const float* __restrict__ mask, const float* __restrict__ tb,
    const ushort* __restrict__ WP, const float* __restrict__ bg,
    const float* __restrict__ bout, float* __restrict__ out)
{
    __shared__ ushort zlds[48][132];     // LN'd halo rows, bf16 (+4 pad)
    __shared__ ushort kl[48][NH][40];    // K halo (slot 47 = spill pad, never read)
    __shared__ ushort vl[48][NH][40];
    __shared__ ushort qb[32][136];       // Q for own 32 rows
    __shared__ ushort gb[32][136];       // sigmoid gate
    __shared__ float  ml[48];
    ushort (*po)[136] = (ushort (*)[136])&zlds[0][0];  // gated output; zlds dead by then

    const int i   = blockIdx.y;
    const int j0  = blockIdx.x * 32;
    const int tid = threadIdx.x;
    const int wid = tid >> 6, lane = tid & 63;
    const int l16 = lane & 15, lk = lane >> 4;

    // ---- Phase 1: LN of 48 halo slots (2 passes of 32 rows; 16 lanes x 8ch per row) ----
    #pragma unroll
    for (int pass = 0; pass < 2; ++pass) {
        const int r = pass*32 + (tid >> 4);
        if (r < 48) {
            const int li  = tid & 15;
            const int jj  = j0 - 8 + r;
            const int jjc = min(max(jj, 0), N-1);
            const float* zr = z + ((size_t)i*N + jjc)*CZ + li*8;
            float4 a = ((const float4*)zr)[0];
            float4 b = ((const float4*)zr)[1];
            float s  = a.x+a.y+a.z+a.w + b.x+b.y+b.z+b.w;
            float s2 = a.x*a.x+a.y*a.y+a.z*a.z+a.w*a.w + b.x*b.x+b.y*b.y+b.z*b.z+b.w*b.w;
            #pragma unroll
            for (int off=1; off<16; off<<=1) { s += __shfl_xor(s, off); s2 += __shfl_xor(s2, off); }
            const float mu   = s * (1.f/CZ);
            const float rstd = rsqrtf(s2*(1.f/CZ) - mu*mu + 1e-5f);
            const int c0 = li*8;
            float vals[8] = {a.x,a.y,a.z,a.w,b.x,b.y,b.z,b.w};
            uint4 pk; ushort* ph = (ushort*)&pk;
            #pragma unroll
            for (int t=0; t<8; t++)
                ph[t] = f2bf((vals[t]-mu)*rstd*lnw[c0+t] + lnb[c0+t]);
            *(uint4*)&zlds[r][c0] = pk;
        }
    }
    if (tid < 47) {
        const int jj  = j0 - 8 + tid;
        const int jjc = min(max(jj, 0), N-1);
        const bool ok = (jj >= 0) && (jj < N) && (mask[(size_t)i*N + jjc] > 0.f);
        ml[tid] = ok ? 0.f : -1e9f;
    }
    __syncthreads();

    // ---- Phase 2: projections. 10 tile-jobs split over 8 waves (5 per half). ----
    {
        const int cw   = wid & 3;     // column quarter (= head for kl/vl)
        const int half = wid >> 2;

        bf16x8 bfrag[2][4];
        auto loadB = [&](int m) {
            #pragma unroll
            for (int nt2=0; nt2<2; nt2++)
                #pragma unroll
                for (int ks=0; ks<4; ks++)
                    bfrag[nt2][ks] = *(const bf16x8*)(WP + (size_t)m*16384 + (cw*2+nt2)*2048 + ks*512 + lane*8);
        };
        auto projKV = [&](int slot0, ushort (*dst)[NH][40]) {
            bf16x8 af[4];
            #pragma unroll
            for (int ks=0; ks<4; ks++)
                af[ks] = *(const bf16x8*)&zlds[slot0 + l16][ks*32 + lk*8];
            #pragma unroll
            for (int nt2=0; nt2<2; nt2++) {
                f32x4 acc = {0.f,0.f,0.f,0.f};
                #pragma unroll
                for (int ks=0; ks<4; ks++)   // swapped -> C^T: row=slot0+l16
                    acc = __builtin_amdgcn_mfma_f32_16x16x32_bf16(bfrag[nt2][ks], af[ks], acc, 0, 0, 0);
                uint2 pk2;
                pk2.x = (unsigned)f2bf(acc[0]) | ((unsigned)f2bf(acc[1])<<16);
                pk2.y = (unsigned)f2bf(acc[2]) | ((unsigned)f2bf(acc[3])<<16);
                *(uint2*)&dst[slot0 + l16][cw][nt2*16 + lk*4] = pk2;
            }
        };
        auto projQG = [&](int slot0, ushort (*dst)[136], bool gate) {
            float4 bg4[2];
            if (gate)
                #pragma unroll
                for (int nt2=0; nt2<2; nt2++)
                    bg4[nt2] = *(const float4*)(bg + cw*32 + nt2*16 + lk*4);
            bf16x8 af[4];
            #pragma unroll
            for (int ks=0; ks<4; ks++)
                af[ks] = *(const bf16x8*)&zlds[slot0 + l16][ks*32 + lk*8];
            #pragma unroll
            for (int nt2=0; nt2<2; nt2++) {
                f32x4 acc = {0.f,0.f,0.f,0.f};
                #pragma unroll
                for (int ks=0; ks<4; ks++)
                    acc = __builtin_amdgcn_mfma_f32_16x16x32_bf16(bfrag[nt2][ks], af[ks], acc, 0, 0, 0);
                float v0,v1,v2,v3;
                if (gate) {
                    v0 = 1.f/(1.f + __expf(-(acc[0] + bg4[nt2].x)));
                    v1 = 1.f/(1.f + __expf(-(acc[1] + bg4[nt2].y)));
                    v2 = 1.f/(1.f + __expf(-(acc[2] + bg4[nt2].z)));
                    v3 = 1.f/(1.f + __expf(-(acc[3] + bg4[nt2].w)));
                } else { v0=acc[0]; v1=acc[1]; v2=acc[2]; v3=acc[3]; }
                uint2 pk2;
                pk2.x = (unsigned)f2bf(v0) | ((unsigned)f2bf(v1)<<16);
                pk2.y = (unsigned)f2bf(v2) | ((unsigned)f2bf(v3)<<16);
                *(uint2*)&dst[slot0 - 8 + l16][cw*32 + nt2*16 + lk*4] = pk2;
            }
        };

        if (half == 0) {
            loadB(1); projKV(0, kl); projKV(16, kl); projKV(32, kl);   // K
            loadB(2); projKV(0, vl); projKV(16, vl);                   // V (part)
        } else {
            loadB(2); projKV(32, vl);                                  // V (rest)
            loadB(0); projQG(8, qb, false); projQG(24, qb, false);     // Q
            loadB(3); projQG(8, gb, true);  projQG(24, gb, true);      // G
        }
    }
    __syncthreads();

    // ---- Phase 3: windowed attention (thread = (jloc, h, cq)): 8 channels each ----
    const int cq   = tid & 3;
    const int h    = (tid >> 2) & 3;
    const int jloc = tid >> 4;
    const int j    = j0 + jloc;
    const int c0l  = cq * 8;

    float qv[8];
    {
        uint4 q1 = *(const uint4*)&qb[jloc][h*CH + c0l];
        const ushort* s1 = (const ushort*)&q1;
        #pragma unroll
        for (int t=0; t<8; t++) qv[t] = bf2f(s1[t]);
    }

    const float scale = 0.17677669529663688f; // 1/sqrt(32)
    float lg[WIN];
    #pragma unroll
    for (int w=0; w<WIN; w++) {
        const int rel = jloc + w;
        float dot = 0.f;
        {
            uint4 kv = *(const uint4*)&kl[rel][h][c0l];
            const ushort* kp = (const ushort*)&kv;
            #pragma unroll
            for (int t=0; t<8; t++) dot += qv[t]*bf2f(kp[t]);
        }
        dot += __shfl_xor(dot, 1);
        dot += __shfl_xor(dot, 2);          // combine the four c-quarters
        const int jj  = j - 8 + w;
        const int jjc = min(max(jj, 0), N-1);
        lg[w] = dot*scale + tb[((size_t)j*N + jjc)*4 + h] + ml[rel];
    }
    float mx = lg[0];
    #pragma unroll
    for (int w=1; w<WIN; w++) mx = fmaxf(mx, lg[w]);
    float sum = 0.f;
    #pragma unroll
    for (int w=0; w<WIN; w++) { lg[w] = __expf(lg[w]-mx); sum += lg[w]; }
    const float inv = 1.f/sum;

    float o[8];
    #pragma unroll
    for (int c=0; c<8; c++) o[c] = 0.f;
    #pragma unroll
    for (int w=0; w<WIN; w++) {
        const float p   = lg[w]*inv;
        const int   rel = jloc + w;
        uint4 vv = *(const uint4*)&vl[rel][h][c0l];
        const ushort* vp = (const ushort*)&vv;
        #pragma unroll
        for (int t=0; t<8; t++) o[t] += p*bf2f(vp[t]);
    }

    {
        uint4 g1 = *(const uint4*)&gb[jloc][h*CH + c0l];
        const ushort* s1 = (const ushort*)&g1;
        uint4 o1; ushort* p1 = (ushort*)&o1;
        #pragma unroll
        for (int t=0; t<8; t++) p1[t] = f2bf(o[t] * bf2f(s1[t]));
        *(uint4*)&po[jloc][h*CH + c0l] = o1;   // po aliases zlds (dead since phase 2)
    }

    // ---- Phase 4: out-GEMM. Wave = (rt, col-quarter): 1 row-tile x 32 cols each ----
    const int rt  = wid >> 2;
    const int cwo = wid & 3;
    bf16x8 bfrag[2][4];
    float4 bo4[2];
    #pragma unroll
    for (int nt2=0; nt2<2; nt2++) {
        #pragma unroll
        for (int ks=0; ks<4; ks++)
            bfrag[nt2][ks] = *(const bf16x8*)(WP + (size_t)4*16384 + (cwo*2+nt2)*2048 + ks*512 + lane*8);
        bo4[nt2] = *(const float4*)(bout + cwo*32 + nt2*16 + lk*4);
    }
    __syncthreads();

    {
        bf16x8 af[4];
        #pragma unroll
        for (int ks=0; ks<4; ks++)
            af[ks] = *(const bf16x8*)&po[rt*16 + l16][ks*32 + lk*8];
        const size_t orow = (size_t)(i*N + j0 + rt*16 + l16)*CZ;
        #pragma unroll
        for (int nt2=0; nt2<2; nt2++) {
            f32x4 acc = {0.f,0.f,0.f,0.f};
            #pragma unroll
            for (int ks=0; ks<4; ks++)   // swapped -> C^T: row=l16, 4 consecutive cols
                acc = __builtin_amdgcn_mfma_f32_16x16x32_bf16(bfrag[nt2][ks], af[ks], acc, 0, 0, 0);
            float4 ov;
            ov.x = acc[0] + bo4[nt2].x; ov.y = acc[1] + bo4[nt2].y;
            ov.z = acc[2] + bo4[nt2].z; ov.w = acc[3] + bo4[nt2].w;
            *(float4*)(out + orow + cwo*32 + nt2*16 + lk*4) = ov;
        }
    }
}

extern "C" void kernel_launch(void* const* d_in, const int* in_sizes, int n_in,
                              void* d_out, int out_size, void* d_ws, size_t ws_size,
                              hipStream_t stream)
{
    const float* z    = (const float*)d_in[0];
    const float* mask = (const float*)d_in[1];
    const float* lnw  = (const float*)d_in[2];
    const float* lnb  = (const float*)d_in[3];
    const float* wq   = (const float*)d_in[4];
    const float* wk   = (const float*)d_in[5];
    const float* wv   = (const float*)d_in[6];
    const float* wb   = (const float*)d_in[7];
    const float* wg   = (const float*)d_in[8];
    const float* bg   = (const float*)d_in[9];
    const float* wo   = (const float*)d_in[10];
    const float* bo   = (const float*)d_in[11];

    float*  tb = (float*)d_ws;                      // f32 [NROWS][4]
    ushort* WP = (ushort*)(tb + (size_t)NROWS*4);   // 5 x 16384 bf16, fragment-ordered
    if (ws_size < (size_t)NROWS*4*sizeof(float) + 5*16384*sizeof(ushort)) return;

    k_tb_pack<<<NROWS/16, 256, 0, stream>>>(z, lnw, lnb, wb, tb, wq, wk, wv, wg, wo, WP);
    k_fused  <<<dim3(N/32, N), 512, 0, stream>>>(z, lnw, lnb, mask, tb, WP, bg, bo, (float*)d_out);
}

// Round 20
// 45.267 us; speedup vs baseline: 1.4191x; 1.1007x over previous
//
#include <hip/hip_runtime.h>
#include <hip/hip_bf16.h>

#define N 192
#define CZ 128
#define NH 4
#define CH 32
#define WIN 16
#define NROWS (N*N)   // 36864

typedef __attribute__((ext_vector_type(8))) short bf16x8;
typedef __attribute__((ext_vector_type(4))) float f32x4;

static __device__ __forceinline__ ushort f2bf(float x){
    union{float f; unsigned u;} a; a.f = x;
    unsigned r = a.u + 0x7fffu + ((a.u>>16)&1u);   // RNE
    return (ushort)(r>>16);
}
static __device__ __forceinline__ float bf2f(ushort s){
    union{unsigned u; float f;} a; a.u = ((unsigned)s)<<16;
    return a.f;
}

// ---------------- K1: LN + triangle-bias projection, weight-packing piggybacked ----------------
__global__ __launch_bounds__(256) void k_tb_pack(
    const float* __restrict__ z, const float* __restrict__ lnw, const float* __restrict__ lnb,
    const float* __restrict__ wbias, float* __restrict__ tb,
    const float* __restrict__ wq, const float* __restrict__ wk,
    const float* __restrict__ wv, const float* __restrict__ wg,
    const float* __restrict__ wo, ushort* __restrict__ WP)
{
    const int tid = threadIdx.x;
    if (blockIdx.x < 40) {
        const int m = blockIdx.x >> 3;
        const float* W = (m==0)?wq:(m==1)?wk:(m==2)?wv:(m==3)?wg:wo;
        const int f = (blockIdx.x & 7)*256 + tid;       // fragment index 0..2047
        const int nt = f >> 8, ks = (f >> 6) & 3, lane8 = f & 63;
        const int col = nt*16 + (lane8 & 15);
        const int r0  = ks*32 + (lane8 >> 4)*8;
        ushort tmp[8];
        #pragma unroll
        for (int i=0; i<8; i++) tmp[i] = f2bf(W[(size_t)(r0+i)*CZ + col]);
        *(uint4*)(WP + (size_t)m*16384 + (size_t)f*8) = *(uint4*)tmp;
    }
    const int wave = tid >> 6, lane = tid & 63;
    const int r  = wave*4 + (lane >> 4);
    const int li = lane & 15;
    const int row = blockIdx.x*16 + r;
    const float* zr = z + (size_t)row*CZ + li*8;
    float4 a = ((const float4*)zr)[0];
    float4 b = ((const float4*)zr)[1];
    float s  = a.x+a.y+a.z+a.w + b.x+b.y+b.z+b.w;
    float s2 = a.x*a.x+a.y*a.y+a.z*a.z+a.w*a.w + b.x*b.x+b.y*b.y+b.z*b.z+b.w*b.w;
    #pragma unroll
    for (int off=1; off<16; off<<=1) { s += __shfl_xor(s, off); s2 += __shfl_xor(s2, off); }
    const float mu   = s * (1.f/CZ);
    const float rstd = rsqrtf(s2*(1.f/CZ) - mu*mu + 1e-5f);
    const int c0 = li*8;
    float vals[8] = {a.x,a.y,a.z,a.w,b.x,b.y,b.z,b.w};
    float tbp[4] = {0.f,0.f,0.f,0.f};
    #pragma unroll
    for (int t=0; t<8; t++) {
        const float nv = (vals[t]-mu)*rstd*lnw[c0+t] + lnb[c0+t];
        float4 wb4 = *(const float4*)(wbias + (c0+t)*4);
        tbp[0] += nv*wb4.x; tbp[1] += nv*wb4.y;
        tbp[2] += nv*wb4.z; tbp[3] += nv*wb4.w;
    }
    #pragma unroll
    for (int off=1; off<16; off<<=1) {
        #pragma unroll
        for (int h=0; h<4; h++) tbp[h] += __shfl_xor(tbp[h], off);
    }
    if (li == 0) *(float4*)(tb + (size_t)row*4) = make_float4(tbp[0],tbp[1],tbp[2],tbp[3]);
}

// ---------------- K2: fused LN + Q/K/V/G proj + attention + gate + out-GEMM ----------------
// 256 threads, LDS 52.3KB -> 3 blocks/CU (1.5 rounds vs 2.25), launch_bounds(256,3) -> VGPR<=170
// (no register strangling). Gate carried in regs across one barrier, lands in dead-zlds overlay.
__global__ __launch_bounds__(256, 3) void k_fused(
    const float* __restrict__ z, const float* __restrict__ lnw, const float* __restrict__ lnb,
    const float* __restrict__ mask, const float* __restrict__ tb,
    const ushort* __restrict__ WP, const float* __restrict__ bg,
    const float* __restrict__ bout, float* __restrict__ out)
{
    __shared__ ushort zlds[48][132];     // LN'd halo rows, bf16 (+4 pad)
    __shared__ ushort kl[48][NH][40];    // K halo (slot 47 = spill pad, never read)
    __shared__ ushort vl[48][NH][40];
    __shared__ ushort qb[32][136];       // Q for own 32 rows
    __shared__ float  ml[48];
    ushort (*gpo)[136] = (ushort (*)[136])&zlds[0][0];  // gate, then gated output (4352<=6336 ushorts)

    const int i   = blockIdx.y;
    const int j0  = blockIdx.x * 32;
    const int tid = threadIdx.x;
    const int wid = tid >> 6, lane = tid & 63;
    const int l16 = lane & 15, lk = lane >> 4;

    // ---- Phase 1: LN of 48 halo slots (3 x 16 rows; 16 lanes x 8ch per row) ----
    for (int it = 0; it < 3; ++it) {
        const int r   = it*16 + wid*4 + lk;
        const int jj  = j0 - 8 + r;
        const int jjc = min(max(jj, 0), N-1);
        const float* zr = z + ((size_t)i*N + jjc)*CZ + l16*8;
        float4 a = ((const float4*)zr)[0];
        float4 b = ((const float4*)zr)[1];
        float s  = a.x+a.y+a.z+a.w + b.x+b.y+b.z+b.w;
        float s2 = a.x*a.x+a.y*a.y+a.z*a.z+a.w*a.w + b.x*b.x+b.y*b.y+b.z*b.z+b.w*b.w;
        #pragma unroll
        for (int off=1; off<16; off<<=1) { s += __shfl_xor(s, off); s2 += __shfl_xor(s2, off); }
        const float mu   = s * (1.f/CZ);
        const float rstd = rsqrtf(s2*(1.f/CZ) - mu*mu + 1e-5f);
        const int c0 = l16*8;
        float vals[8] = {a.x,a.y,a.z,a.w,b.x,b.y,b.z,b.w};
        uint4 pk; ushort* ph = (ushort*)&pk;
        #pragma unroll
        for (int t=0; t<8; t++)
            ph[t] = f2bf((vals[t]-mu)*rstd*lnw[c0+t] + lnb[c0+t]);
        *(uint4*)&zlds[r][c0] = pk;
    }
    if (tid < 47) {
        const int jj  = j0 - 8 + tid;
        const int jjc = min(max(jj, 0), N-1);
        const bool ok = (jj >= 0) && (jj < N) && (mask[(size_t)i*N + jjc] > 0.f);
        ml[tid] = ok ? 0.f : -1e9f;
    }
    __syncthreads();                                    // B1

    // ---- Phase 2: projections. Wave = column quarter cw = wid. G -> registers. ----
    uint2 gst0[2], gst1[2];
    {
        const int cw = wid;
        bf16x8 bfrag[2][4];
        auto loadB = [&](int m) {
            #pragma unroll
            for (int nt2=0; nt2<2; nt2++)
                #pragma unroll
                for (int ks=0; ks<4; ks++)
                    bfrag[nt2][ks] = *(const bf16x8*)(WP + (size_t)m*16384 + (cw*2+nt2)*2048 + ks*512 + lane*8);
        };
        auto projKV = [&](int slot0, ushort (*dst)[NH][40]) {
            bf16x8 af[4];
            #pragma unroll
            for (int ks=0; ks<4; ks++)
                af[ks] = *(const bf16x8*)&zlds[slot0 + l16][ks*32 + lk*8];
            #pragma unroll
            for (int nt2=0; nt2<2; nt2++) {
                f32x4 acc = {0.f,0.f,0.f,0.f};
                #pragma unroll
                for (int ks=0; ks<4; ks++)   // swapped -> C^T: row=slot0+l16
                    acc = __builtin_amdgcn_mfma_f32_16x16x32_bf16(bfrag[nt2][ks], af[ks], acc, 0, 0, 0);
                uint2 pk2;
                pk2.x = (unsigned)f2bf(acc[0]) | ((unsigned)f2bf(acc[1])<<16);
                pk2.y = (unsigned)f2bf(acc[2]) | ((unsigned)f2bf(acc[3])<<16);
                *(uint2*)&dst[slot0 + l16][cw][nt2*16 + lk*4] = pk2;
            }
        };
        auto projQ = [&](int slot0) {
            bf16x8 af[4];
            #pragma unroll
            for (int ks=0; ks<4; ks++)
                af[ks] = *(const bf16x8*)&zlds[slot0 + l16][ks*32 + lk*8];
            #pragma unroll
            for (int nt2=0; nt2<2; nt2++) {
                f32x4 acc = {0.f,0.f,0.f,0.f};
                #pragma unroll
                for (int ks=0; ks<4; ks++)
                    acc = __builtin_amdgcn_mfma_f32_16x16x32_bf16(bfrag[nt2][ks], af[ks], acc, 0, 0, 0);
                uint2 pk2;
                pk2.x = (unsigned)f2bf(acc[0]) | ((unsigned)f2bf(acc[1])<<16);
                pk2.y = (unsigned)f2bf(acc[2]) | ((unsigned)f2bf(acc[3])<<16);
                *(uint2*)&qb[slot0 - 8 + l16][cw*32 + nt2*16 + lk*4] = pk2;
            }
        };
        auto projG = [&](int slot0, uint2* gs) {
            float4 bg4[2];
            #pragma unroll
            for (int nt2=0; nt2<2; nt2++)
                bg4[nt2] = *(const float4*)(bg + cw*32 + nt2*16 + lk*4);
            bf16x8 af[4];
            #pragma unroll
            for (int ks=0; ks<4; ks++)
                af[ks] = *(const bf16x8*)&zlds[slot0 + l16][ks*32 + lk*8];
            #pragma unroll
            for (int nt2=0; nt2<2; nt2++) {
                f32x4 acc = {0.f,0.f,0.f,0.f};
                #pragma unroll
                for (int ks=0; ks<4; ks++)
                    acc = __builtin_amdgcn_mfma_f32_16x16x32_bf16(bfrag[nt2][ks], af[ks], acc, 0, 0, 0);
                const float v0 = 1.f/(1.f + __expf(-(acc[0] + bg4[nt2].x)));
                const float v1 = 1.f/(1.f + __expf(-(acc[1] + bg4[nt2].y)));
                const float v2 = 1.f/(1.f + __expf(-(acc[2] + bg4[nt2].z)));
                const float v3 = 1.f/(1.f + __expf(-(acc[3] + bg4[nt2].w)));
                uint2 pk2;
                pk2.x = (unsigned)f2bf(v0) | ((unsigned)f2bf(v1)<<16);
                pk2.y = (unsigned)f2bf(v2) | ((unsigned)f2bf(v3)<<16);
                gs[nt2] = pk2;
            }
        };

        loadB(1); projKV(0, kl); projKV(16, kl); projKV(32, kl);   // K
        loadB(2); projKV(0, vl); projKV(16, vl); projKV(32, vl);   // V
        loadB(0); projQ(8);  projQ(24);                            // Q
        loadB(3); projG(8, gst0); projG(24, gst1);                 // G -> regs
    }
    __syncthreads();                                    // B2: zlds reads done, now dead
    {   // land G into the zlds overlay (16B-aligned [136] stride)
        const int cw = wid;
        *(uint2*)&gpo[l16     ][cw*32      + lk*4] = gst0[0];
        *(uint2*)&gpo[l16     ][cw*32 + 16 + lk*4] = gst0[1];
        *(uint2*)&gpo[16 + l16][cw*32      + lk*4] = gst1[0];
        *(uint2*)&gpo[16 + l16][cw*32 + 16 + lk*4] = gst1[1];
    }
    __syncthreads();                                    // B3: G visible to all waves

    // ---- Phase 3: windowed attention (thread = (jloc, h, chalf)): 16 channels each ----
    const int chalf = tid & 1;
    const int h     = (tid >> 1) & 3;
    const int jloc  = tid >> 3;
    const int j     = j0 + jloc;
    const int c0l   = chalf * 16;

    float qv[16];
    {
        uint4 q1 = *(const uint4*)&qb[jloc][h*CH + c0l];
        uint4 q2 = *(const uint4*)&qb[jloc][h*CH + c0l + 8];
        const ushort* s1 = (const ushort*)&q1;
        const ushort* s2 = (const ushort*)&q2;
        #pragma unroll
        for (int t=0; t<8; t++) { qv[t] = bf2f(s1[t]); qv[8+t] = bf2f(s2[t]); }
    }

    const float scale = 0.17677669529663688f; // 1/sqrt(32)
    float lg[WIN];
    #pragma unroll
    for (int w=0; w<WIN; w++) {
        const int rel = jloc + w;
        float dot = 0.f;
        #pragma unroll
        for (int c4=0; c4<2; c4++) {
            uint4 kv = *(const uint4*)&kl[rel][h][c0l + c4*8];
            const ushort* kp = (const ushort*)&kv;
            #pragma unroll
            for (int t=0; t<8; t++) dot += qv[c4*8+t]*bf2f(kp[t]);
        }
        dot += __shfl_xor(dot, 1);
        const int jj  = j - 8 + w;
        const int jjc = min(max(jj, 0), N-1);
        lg[w] = dot*scale + tb[((size_t)j*N + jjc)*4 + h] + ml[rel];
    }
    float mx = lg[0];
    #pragma unroll
    for (int w=1; w<WIN; w++) mx = fmaxf(mx, lg[w]);
    float sum = 0.f;
    #pragma unroll
    for (int w=0; w<WIN; w++) { lg[w] = __expf(lg[w]-mx); sum += lg[w]; }
    const float inv = 1.f/sum;

    float o[16];
    #pragma unroll
    for (int c=0; c<16; c++) o[c] = 0.f;
    #pragma unroll
    for (int w=0; w<WIN; w++) {
        const float p   = lg[w]*inv;
        const int   rel = jloc + w;
        #pragma unroll
        for (int c4=0; c4<2; c4++) {
            uint4 vv = *(const uint4*)&vl[rel][h][c0l + c4*8];
            const ushort* vp = (const ushort*)&vv;
            #pragma unroll
            for (int t=0; t<8; t++) o[c4*8+t] += p*bf2f(vp[t]);
        }
    }

    {   // gate (from gpo) * o -> write back into gpo (same elements, thread-local RMW)
        uint4 g1 = *(const uint4*)&gpo[jloc][h*CH + c0l];
        uint4 g2 = *(const uint4*)&gpo[jloc][h*CH + c0l + 8];
        const ushort* s1 = (const ushort*)&g1;
        const ushort* s2 = (const ushort*)&g2;
        uint4 o1, o2; ushort* p1 = (ushort*)&o1; ushort* p2 = (ushort*)&o2;
        #pragma unroll
        for (int t=0; t<8; t++) {
            p1[t] = f2bf(o[t]   * bf2f(s1[t]));
            p2[t] = f2bf(o[8+t] * bf2f(s2[t]));
        }
        *(uint4*)&gpo[jloc][h*CH + c0l]     = o1;
        *(uint4*)&gpo[jloc][h*CH + c0l + 8] = o2;
    }

    // prefetch out-GEMM B + bias while waiting
    const int cwo = wid;
    bf16x8 bfrag[2][4];
    float4 bo4[2];
    #pragma unroll
    for (int nt2=0; nt2<2; nt2++) {
        #pragma unroll
        for (int ks=0; ks<4; ks++)
            bfrag[nt2][ks] = *(const bf16x8*)(WP + (size_t)4*16384 + (cwo*2+nt2)*2048 + ks*512 + lane*8);
        bo4[nt2] = *(const float4*)(bout + cwo*32 + nt2*16 + lk*4);
    }
    __syncthreads();                                    // B4: gated output visible

    // ---- Phase 4: out-GEMM. Wave = col-quarter, 2 row-tiles each ----
    #pragma unroll
    for (int rt=0; rt<2; rt++) {
        bf16x8 af[4];
        #pragma unroll
        for (int ks=0; ks<4; ks++)
            af[ks] = *(const bf16x8*)&gpo[rt*16 + l16][ks*32 + lk*8];
        const size_t orow = (size_t)(i*N + j0 + rt*16 + l16)*CZ;
        #pragma unroll
        for (int nt2=0; nt2<2; nt2++) {
            f32x4 acc = {0.f,0.f,0.f,0.f};
            #pragma unroll
            for (int ks=0; ks<4; ks++)   // swapped -> C^T: row=l16, 4 consecutive cols
                acc = __builtin_amdgcn_mfma_f32_16x16x32_bf16(bfrag[nt2][ks], af[ks], acc, 0, 0, 0);
            float4 ov;
            ov.x = acc[0] + bo4[nt2].x; ov.y = acc[1] + bo4[nt2].y;
            ov.z = acc[2] + bo4[nt2].z; ov.w = acc[3] + bo4[nt2].w;
            *(float4*)(out + orow + cwo*32 + nt2*16 + lk*4) = ov;
        }
    }
}

extern "C" void kernel_launch(void* const* d_in, const int* in_sizes, int n_in,
                              void* d_out, int out_size, void* d_ws, size_t ws_size,
                              hipStream_t stream)
{
    const float* z    = (const float*)d_in[0];
    const float* mask = (const float*)d_in[1];
    const float* lnw  = (const float*)d_in[2];
    const float* lnb  = (const float*)d_in[3];
    const float* wq   = (const float*)d_in[4];
    const float* wk   = (const float*)d_in[5];
    const float* wv   = (const float*)d_in[6];
    const float* wb   = (const float*)d_in[7];
    const float* wg   = (const float*)d_in[8];
    const float* bg   = (const float*)d_in[9];
    const float* wo   = (const float*)d_in[10];
    const float* bo   = (const float*)d_in[11];

    float*  tb = (float*)d_ws;                      // f32 [NROWS][4]
    ushort* WP = (ushort*)(tb + (size_t)NROWS*4);   // 5 x 16384 bf16, fragment-ordered
    if (ws_size < (size_t)NROWS*4*sizeof(float) + 5*16384*sizeof(ushort)) return;

    k_tb_pack<<<NROWS/16, 256, 0, stream>>>(z, lnw, lnb, wb, tb, wq, wk, wv, wg, wo, WP);
    k_fused  <<<dim3(N/32, N), 256, 0, stream>>>(z, lnw, lnb, mask, tb, WP, bg, bo, (float*)d_out);
}